// Round 4
// baseline (143.095 us; speedup 1.0000x reference)
//
#include <hip/hip_runtime.h>

constexpr int BSZ = 512;
constexpr int DIM = 128;
constexpr int NREG = 6;                 // 6*64 = 384 register-cached negative slots
#define MARGIN_F 0.2f
#define EPS_F 1e-6f

struct Accum { double num; unsigned long long den; unsigned int done; unsigned int pad; };

// One block (512 threads = 8 waves) per anchor i.
// Phase 1: thread t computes D[i,t]; ballot-compacts into apos (+margin) / bneg.
// Phase 2: each lane register-caches 6 negatives; waves stride over positives
//          read as uniform-address float4 broadcasts from LDS.
// Finish:  global atomic accumulate; last block writes out = num/den.
// NOTE: kernel_launch's first node MUST be the blit-queue hipMemsetAsync —
// it serializes this graph behind the harness's 264 MB workspace poison
// (same DMA engine). Replacing it with an init kernel made the main kernel
// overlap the poison stream: FETCH_SIZE 1.6 MB -> 71 MB, dur 55 -> 83 us.
__global__ __launch_bounds__(512, 4) void triplet_main(
    const float* __restrict__ feat, const int* __restrict__ mask,
    Accum* __restrict__ g, float* __restrict__ out, int nblocks) {
  const int i = blockIdx.x;
  const int tid = threadIdx.x;
  const int wave = tid >> 6;
  const int lane = tid & 63;

  __shared__ float fis[DIM];        // anchor row + EPS folded in
  __shared__ float apos[BSZ];       // compacted positives (+margin), pad -1e30
  __shared__ float bneg[BSZ];       // compacted negatives, padded to 384 w/ +1e30
  __shared__ int wtot[8][2];
  __shared__ float wred[8];

  if (tid < DIM / 4) {
    float4 v = ((const float4*)(feat + (size_t)i * DIM))[tid];
    fis[tid * 4 + 0] = v.x + EPS_F; fis[tid * 4 + 1] = v.y + EPS_F;
    fis[tid * 4 + 2] = v.z + EPS_F; fis[tid * 4 + 3] = v.w + EPS_F;
  }
  __syncthreads();

  // ---- Phase 1: distance for column t = tid, then ballot compaction ----
  const float4* fk = (const float4*)(feat + (size_t)tid * DIM);
  float s = 0.f;
#pragma unroll
  for (int d = 0; d < DIM / 4; ++d) {
    float4 v = fk[d];
    float x0 = fis[4 * d + 0] - v.x;
    float x1 = fis[4 * d + 1] - v.y;
    float x2 = fis[4 * d + 2] - v.z;
    float x3 = fis[4 * d + 3] - v.w;
    s = fmaf(x0, x0, s); s = fmaf(x1, x1, s);
    s = fmaf(x2, x2, s); s = fmaf(x3, x3, s);
  }
  const float dist = sqrtf(s);
  const int m = mask[(size_t)i * BSZ + tid];
  const bool is_pos = (m != 0);
  const bool is_neg = (m == 0) && (tid != i);

  const unsigned long long bp = __ballot(is_pos);
  const unsigned long long bn = __ballot(is_neg);
  const unsigned long long ltm = (1ull << lane) - 1ull;
  const int p_before = __popcll(bp & ltm);
  const int n_before = __popcll(bn & ltm);
  if (lane == 0) { wtot[wave][0] = __popcll(bp); wtot[wave][1] = __popcll(bn); }
  __syncthreads();

  int pbase = 0, nbase = 0, nP = 0, nN = 0;
#pragma unroll
  for (int w = 0; w < 8; ++w) {
    const int tp = wtot[w][0], tn = wtot[w][1];
    if (w < wave) { pbase += tp; nbase += tn; }
    nP += tp; nN += tn;
  }
  if (is_pos)      apos[pbase + p_before] = dist + MARGIN_F;
  else if (is_neg) bneg[nbase + n_before] = dist;

  const int nPpad = (nP + 31) & ~31;                 // mult of 32 -> nPpad/4 mult of 8
  { const int j = nP + tid; if (j < nPpad) apos[j] = -1e30f; }   // relu -> 0
  { const int k = nN + tid; if (k < NREG * 64) bneg[k] = 1e30f; } // relu -> 0
  __syncthreads();

  // ---- Phase 2: register-cached negatives, broadcast positives ----
  float bnr[NREG];
#pragma unroll
  for (int r = 0; r < NREG; ++r) bnr[r] = bneg[lane + 64 * r];

  float acc[NREG];
#pragma unroll
  for (int r = 0; r < NREG; ++r) acc[r] = 0.f;

  const float4* apos4 = (const float4*)apos;
  const int nj4 = nPpad >> 2;
  for (int j4 = wave; j4 < nj4; j4 += 8) {
    const float4 a = apos4[j4];                      // uniform addr: LDS broadcast
#pragma unroll
    for (int r = 0; r < NREG; ++r) {
      acc[r] += fmaxf(a.x - bnr[r], 0.f);
      acc[r] += fmaxf(a.y - bnr[r], 0.f);
      acc[r] += fmaxf(a.z - bnr[r], 0.f);
      acc[r] += fmaxf(a.w - bnr[r], 0.f);
    }
  }
  float lsum = 0.f;
#pragma unroll
  for (int r = 0; r < NREG; ++r) lsum += acc[r];

  if (nN > NREG * 64) {                              // rare statistical tail
    for (int j = wave; j < nP; j += 8) {
      const float aj = apos[j];
      for (int k = NREG * 64 + lane; k < nN; k += 64)
        lsum += fmaxf(aj - bneg[k], 0.f);
    }
  }

  // ---- Block reduction + device accumulate ----
  for (int off = 32; off > 0; off >>= 1) lsum += __shfl_down(lsum, off, 64);
  if (lane == 0) wred[wave] = lsum;
  __syncthreads();
  if (tid == 0) {
    float bsum = 0.f;
#pragma unroll
    for (int w = 0; w < 8; ++w) bsum += wred[w];
    atomicAdd(&g->num, (double)bsum);
    atomicAdd(&g->den, (unsigned long long)((long long)nP * (long long)nN));
    __threadfence();
    const unsigned int old = atomicAdd(&g->done, 1u);
    if (old == (unsigned int)(nblocks - 1)) {
      __threadfence();
      const double num = atomicAdd(&g->num, 0.0);            // device-scope read
      const unsigned long long den = atomicAdd(&g->den, 0ull);
      out[0] = (den > 0) ? (float)(num / (double)den) : 0.0f;
    }
  }
}

extern "C" void kernel_launch(void* const* d_in, const int* in_sizes, int n_in,
                              void* d_out, int out_size, void* d_ws, size_t ws_size,
                              hipStream_t stream) {
  const float* feat = (const float*)d_in[0];
  const int* mask = (const int*)d_in[1];
  float* out = (float*)d_out;
  Accum* g = (Accum*)d_ws;

  // Blit-queue memset as first node: zero-inits the accumulator AND
  // serializes this graph behind the harness's workspace-poison blit.
  hipMemsetAsync(d_ws, 0, sizeof(Accum), stream);
  triplet_main<<<BSZ, 512, 0, stream>>>(feat, mask, g, out, BSZ);
}

// Round 5
// 129.269 us; speedup vs baseline: 1.1070x; 1.1070x over previous
//
#include <hip/hip_runtime.h>

constexpr int BSZ = 512;
constexpr int DIM = 128;
constexpr int NREG = 6;                 // 6*64 = 384 register-cached negative slots
#define MARGIN_F 0.2f
#define EPS_F 1e-6f

// One block (512 threads = 8 waves) per anchor i.
// Phase 1: thread t computes D[i,t]; ballot-compacts into apos (+margin) / bneg.
// Phase 2: each lane register-caches 6 negatives; waves stride over positives
//          read as uniform-address float4 broadcasts from LDS.
// Tail:    per-block partials at DISTINCT addresses (no contended atomics —
//          rounds 3/4's same-cacheline num/den/done atomics from 512 blocks
//          cost ~30 us of serialized coherence traffic), then 1-block finalize.
__global__ __launch_bounds__(512, 4) void triplet_main(
    const float* __restrict__ feat, const int* __restrict__ mask,
    double* __restrict__ num_part, int* __restrict__ den_part) {
  const int i = blockIdx.x;
  const int tid = threadIdx.x;
  const int wave = tid >> 6;
  const int lane = tid & 63;

  __shared__ float fis[DIM];        // anchor row + EPS folded in
  __shared__ float apos[BSZ];       // compacted positives (+margin), pad -1e30
  __shared__ float bneg[BSZ];       // compacted negatives, padded to 384 w/ +1e30
  __shared__ int wtot[8][2];
  __shared__ float wred[8];

  if (tid < DIM / 4) {
    float4 v = ((const float4*)(feat + (size_t)i * DIM))[tid];
    fis[tid * 4 + 0] = v.x + EPS_F; fis[tid * 4 + 1] = v.y + EPS_F;
    fis[tid * 4 + 2] = v.z + EPS_F; fis[tid * 4 + 3] = v.w + EPS_F;
  }
  __syncthreads();

  // ---- Phase 1: distance for column t = tid, then ballot compaction ----
  const float4* fk = (const float4*)(feat + (size_t)tid * DIM);
  float s = 0.f;
#pragma unroll
  for (int d = 0; d < DIM / 4; ++d) {
    float4 v = fk[d];
    float x0 = fis[4 * d + 0] - v.x;
    float x1 = fis[4 * d + 1] - v.y;
    float x2 = fis[4 * d + 2] - v.z;
    float x3 = fis[4 * d + 3] - v.w;
    s = fmaf(x0, x0, s); s = fmaf(x1, x1, s);
    s = fmaf(x2, x2, s); s = fmaf(x3, x3, s);
  }
  const float dist = sqrtf(s);
  const int m = mask[(size_t)i * BSZ + tid];
  const bool is_pos = (m != 0);
  const bool is_neg = (m == 0) && (tid != i);

  const unsigned long long bp = __ballot(is_pos);
  const unsigned long long bn = __ballot(is_neg);
  const unsigned long long ltm = (1ull << lane) - 1ull;
  const int p_before = __popcll(bp & ltm);
  const int n_before = __popcll(bn & ltm);
  if (lane == 0) { wtot[wave][0] = __popcll(bp); wtot[wave][1] = __popcll(bn); }
  __syncthreads();

  int pbase = 0, nbase = 0, nP = 0, nN = 0;
#pragma unroll
  for (int w = 0; w < 8; ++w) {
    const int tp = wtot[w][0], tn = wtot[w][1];
    if (w < wave) { pbase += tp; nbase += tn; }
    nP += tp; nN += tn;
  }
  if (is_pos)      apos[pbase + p_before] = dist + MARGIN_F;
  else if (is_neg) bneg[nbase + n_before] = dist;

  const int nPpad = (nP + 31) & ~31;                 // mult of 32 -> nPpad/4 mult of 8
  { const int j = nP + tid; if (j < nPpad) apos[j] = -1e30f; }   // relu -> 0
  { const int k = nN + tid; if (k < NREG * 64) bneg[k] = 1e30f; } // relu -> 0
  __syncthreads();

  // ---- Phase 2: register-cached negatives, broadcast positives ----
  float bnr[NREG];
#pragma unroll
  for (int r = 0; r < NREG; ++r) bnr[r] = bneg[lane + 64 * r];

  float acc[NREG];
#pragma unroll
  for (int r = 0; r < NREG; ++r) acc[r] = 0.f;

  const float4* apos4 = (const float4*)apos;
  const int nj4 = nPpad >> 2;
  for (int j4 = wave; j4 < nj4; j4 += 8) {
    const float4 a = apos4[j4];                      // uniform addr: LDS broadcast
#pragma unroll
    for (int r = 0; r < NREG; ++r) {
      acc[r] += fmaxf(a.x - bnr[r], 0.f);
      acc[r] += fmaxf(a.y - bnr[r], 0.f);
      acc[r] += fmaxf(a.z - bnr[r], 0.f);
      acc[r] += fmaxf(a.w - bnr[r], 0.f);
    }
  }
  float lsum = 0.f;
#pragma unroll
  for (int r = 0; r < NREG; ++r) lsum += acc[r];

  if (nN > NREG * 64) {                              // rare statistical tail
    for (int j = wave; j < nP; j += 8) {
      const float aj = apos[j];
      for (int k = NREG * 64 + lane; k < nN; k += 64)
        lsum += fmaxf(aj - bneg[k], 0.f);
    }
  }

  // ---- Block reduction + uncontended partial write ----
  for (int off = 32; off > 0; off >>= 1) lsum += __shfl_down(lsum, off, 64);
  if (lane == 0) wred[wave] = lsum;
  __syncthreads();
  if (tid == 0) {
    float bsum = 0.f;
#pragma unroll
    for (int w = 0; w < 8; ++w) bsum += wred[w];
    num_part[i] = (double)bsum;                      // distinct address per block
    den_part[i] = nP * nN;
  }
}

__global__ __launch_bounds__(256) void triplet_finalize(
    const double* __restrict__ num_part, const int* __restrict__ den_part,
    float* __restrict__ out) {
  const int tid = threadIdx.x;
  double n = 0.0;
  long long d = 0;
  for (int i = tid; i < BSZ; i += 256) {
    n += num_part[i];
    d += den_part[i];
  }
  __shared__ double sn[4];
  __shared__ long long sd[4];
  for (int off = 32; off > 0; off >>= 1) {
    n += __shfl_down(n, off, 64);
    d += __shfl_down(d, off, 64);
  }
  if ((tid & 63) == 0) { sn[tid >> 6] = n; sd[tid >> 6] = d; }
  __syncthreads();
  if (tid == 0) {
    const double N = sn[0] + sn[1] + sn[2] + sn[3];
    const long long Dn = sd[0] + sd[1] + sd[2] + sd[3];
    out[0] = (Dn > 0) ? (float)(N / (double)Dn) : 0.0f;
  }
}

extern "C" void kernel_launch(void* const* d_in, const int* in_sizes, int n_in,
                              void* d_out, int out_size, void* d_ws, size_t ws_size,
                              hipStream_t stream) {
  const float* feat = (const float*)d_in[0];
  const int* mask = (const int*)d_in[1];
  float* out = (float*)d_out;

  double* num_part = (double*)d_ws;
  int* den_part = (int*)((char*)d_ws + BSZ * sizeof(double));

  // Partials written unconditionally every call -> no init node needed.
  triplet_main<<<BSZ, 512, 0, stream>>>(feat, mask, num_part, den_part);
  triplet_finalize<<<1, 256, 0, stream>>>(num_part, den_part, out);
}

// Round 8
// 66.754 us; speedup vs baseline: 2.1436x; 1.9365x over previous
//
#include <hip/hip_runtime.h>

constexpr int BSZ = 512;
constexpr int DIM = 128;
constexpr int NREG = 6;                 // 6*64 = 384 register-cached negative slots
#define MARGIN_F 0.2f
#define EPS_F 1e-6f

// Kernel A: materialize D[i,j] = ||f_i - f_j + eps||_2 once, 32x32 tiles.
// 256 blocks x 32 KB coalesced reads = 8 MB total (vs 131 MB when every
// triplet block re-streamed the whole feature matrix uncoalesced; under the
// harness's concurrent 141 MB workspace-poison blit, those re-reads missed
// L2 and became ~71 MB of contended HBM fetch).
__global__ __launch_bounds__(256) void dist_tile(
    const float* __restrict__ feat, float* __restrict__ D) {
  const int bi = blockIdx.x >> 4;       // 1-D grid: 256 blocks -> 16x16 tiles
  const int bj = blockIdx.x & 15;
  const int tid = threadIdx.x;

  __shared__ float4 At[32][33];         // [row][d4], pitch 33 breaks bank aliasing
  __shared__ float4 Bt[32][33];

  const float4* ga = (const float4*)feat + (size_t)bi * 32 * (DIM / 4);
  const float4* gb = (const float4*)feat + (size_t)bj * 32 * (DIM / 4);
#pragma unroll
  for (int k = 0; k < 4; ++k) {
    const int idx = tid + k * 256;      // 0..1023, coalesced
    const int row = idx >> 5;           // 0..31
    const int col = idx & 31;           // 0..31 float4s per row
    float4 va = ga[idx];
    va.x += EPS_F; va.y += EPS_F; va.z += EPS_F; va.w += EPS_F;
    At[row][col] = va;                  // EPS folded: (a+eps)-b == a-b+eps
    Bt[row][col] = gb[idx];
  }
  __syncthreads();

  const int r0 = tid >> 4;              // 0..15
  const int c0 = tid & 15;              // 0..15
  float s00 = 0.f, s01 = 0.f, s10 = 0.f, s11 = 0.f;
#pragma unroll
  for (int d = 0; d < DIM / 4; ++d) {
    const float4 a0 = At[r0][d];
    const float4 a1 = At[r0 + 16][d];
    const float4 b0 = Bt[c0][d];
    const float4 b1 = Bt[c0 + 16][d];
    float x;
    x = a0.x - b0.x; s00 = fmaf(x, x, s00);
    x = a0.y - b0.y; s00 = fmaf(x, x, s00);
    x = a0.z - b0.z; s00 = fmaf(x, x, s00);
    x = a0.w - b0.w; s00 = fmaf(x, x, s00);
    x = a0.x - b1.x; s01 = fmaf(x, x, s01);
    x = a0.y - b1.y; s01 = fmaf(x, x, s01);
    x = a0.z - b1.z; s01 = fmaf(x, x, s01);
    x = a0.w - b1.w; s01 = fmaf(x, x, s01);
    x = a1.x - b0.x; s10 = fmaf(x, x, s10);
    x = a1.y - b0.y; s10 = fmaf(x, x, s10);
    x = a1.z - b0.z; s10 = fmaf(x, x, s10);
    x = a1.w - b0.w; s10 = fmaf(x, x, s10);
    x = a1.x - b1.x; s11 = fmaf(x, x, s11);
    x = a1.y - b1.y; s11 = fmaf(x, x, s11);
    x = a1.z - b1.z; s11 = fmaf(x, x, s11);
    x = a1.w - b1.w; s11 = fmaf(x, x, s11);
  }
  float* Drow0 = D + (size_t)(bi * 32 + r0) * BSZ + bj * 32;
  float* Drow1 = D + (size_t)(bi * 32 + r0 + 16) * BSZ + bj * 32;
  Drow0[c0]      = sqrtf(s00);
  Drow0[c0 + 16] = sqrtf(s01);
  Drow1[c0]      = sqrtf(s10);
  Drow1[c0 + 16] = sqrtf(s11);
}

// Kernel B: one block (512 thr) per anchor. Reads only D-row i (2 KB,
// coalesced) + mask row; ballot-compacts; register-cached negatives vs
// LDS-broadcast positives; uncontended per-block partials.
__global__ __launch_bounds__(512, 4) void triplet_main(
    const float* __restrict__ D, const int* __restrict__ mask,
    double* __restrict__ num_part, int* __restrict__ den_part) {
  const int i = blockIdx.x;
  const int tid = threadIdx.x;
  const int wave = tid >> 6;
  const int lane = tid & 63;

  __shared__ float apos[BSZ];       // compacted positives (+margin), pad -1e30
  __shared__ float bneg[BSZ];       // compacted negatives, padded to 384 w/ +1e30
  __shared__ int wtot[8][2];
  __shared__ float wred[8];

  const float dist = D[(size_t)i * BSZ + tid];     // coalesced dword
  const int m = mask[(size_t)i * BSZ + tid];
  const bool is_pos = (m != 0);
  const bool is_neg = (m == 0) && (tid != i);

  const unsigned long long bp = __ballot(is_pos);
  const unsigned long long bn = __ballot(is_neg);
  const unsigned long long ltm = (1ull << lane) - 1ull;
  const int p_before = __popcll(bp & ltm);
  const int n_before = __popcll(bn & ltm);
  if (lane == 0) { wtot[wave][0] = __popcll(bp); wtot[wave][1] = __popcll(bn); }
  __syncthreads();

  int pbase = 0, nbase = 0, nP = 0, nN = 0;
#pragma unroll
  for (int w = 0; w < 8; ++w) {
    const int tp = wtot[w][0], tn = wtot[w][1];
    if (w < wave) { pbase += tp; nbase += tn; }
    nP += tp; nN += tn;
  }
  if (is_pos)      apos[pbase + p_before] = dist + MARGIN_F;
  else if (is_neg) bneg[nbase + n_before] = dist;

  const int nPpad = (nP + 31) & ~31;
  { const int j = nP + tid; if (j < nPpad) apos[j] = -1e30f; }    // relu -> 0
  { const int k = nN + tid; if (k < NREG * 64) bneg[k] = 1e30f; } // relu -> 0
  __syncthreads();

  float bnr[NREG];
#pragma unroll
  for (int r = 0; r < NREG; ++r) bnr[r] = bneg[lane + 64 * r];

  float acc[NREG];
#pragma unroll
  for (int r = 0; r < NREG; ++r) acc[r] = 0.f;

  const float4* apos4 = (const float4*)apos;
  const int nj4 = nPpad >> 2;
  for (int j4 = wave; j4 < nj4; j4 += 8) {
    const float4 a = apos4[j4];                    // uniform addr: LDS broadcast
#pragma unroll
    for (int r = 0; r < NREG; ++r) {
      acc[r] += fmaxf(a.x - bnr[r], 0.f);
      acc[r] += fmaxf(a.y - bnr[r], 0.f);
      acc[r] += fmaxf(a.z - bnr[r], 0.f);
      acc[r] += fmaxf(a.w - bnr[r], 0.f);
    }
  }
  float lsum = 0.f;
#pragma unroll
  for (int r = 0; r < NREG; ++r) lsum += acc[r];

  if (nN > NREG * 64) {                            // rare statistical tail
    for (int j = wave; j < nP; j += 8) {
      const float aj = apos[j];
      for (int k = NREG * 64 + lane; k < nN; k += 64)
        lsum += fmaxf(aj - bneg[k], 0.f);
    }
  }

  for (int off = 32; off > 0; off >>= 1) lsum += __shfl_down(lsum, off, 64);
  if (lane == 0) wred[wave] = lsum;
  __syncthreads();
  if (tid == 0) {
    float bsum = 0.f;
#pragma unroll
    for (int w = 0; w < 8; ++w) bsum += wred[w];
    num_part[i] = (double)bsum;                    // distinct address per block
    den_part[i] = nP * nN;
  }
}

__global__ __launch_bounds__(256) void triplet_finalize(
    const double* __restrict__ num_part, const int* __restrict__ den_part,
    float* __restrict__ out) {
  const int tid = threadIdx.x;
  double n = 0.0;
  long long d = 0;
  for (int i = tid; i < BSZ; i += 256) {
    n += num_part[i];
    d += den_part[i];
  }
  __shared__ double sn[4];
  __shared__ long long sd[4];
  for (int off = 32; off > 0; off >>= 1) {
    n += __shfl_down(n, off, 64);
    d += __shfl_down(d, off, 64);
  }
  if ((tid & 63) == 0) { sn[tid >> 6] = n; sd[tid >> 6] = d; }
  __syncthreads();
  if (tid == 0) {
    const double N = sn[0] + sn[1] + sn[2] + sn[3];
    const long long Dn = sd[0] + sd[1] + sd[2] + sd[3];
    out[0] = (Dn > 0) ? (float)(N / (double)Dn) : 0.0f;
  }
}

extern "C" void kernel_launch(void* const* d_in, const int* in_sizes, int n_in,
                              void* d_out, int out_size, void* d_ws, size_t ws_size,
                              hipStream_t stream) {
  const float* feat = (const float*)d_in[0];
  const int* mask = (const int*)d_in[1];
  float* out = (float*)d_out;

  float* Dm = (float*)d_ws;                                  // 512*512*4 = 1 MB
  double* num_part = (double*)((char*)d_ws + (1 << 20));
  int* den_part = (int*)((char*)d_ws + (1 << 20) + BSZ * sizeof(double));

  dist_tile<<<256, 256, 0, stream>>>(feat, Dm);              // writes all of Dm
  triplet_main<<<BSZ, 512, 0, stream>>>(Dm, mask, num_part, den_part);
  triplet_finalize<<<1, 256, 0, stream>>>(num_part, den_part, out);
}